// Round 4
// baseline (547.753 us; speedup 1.0000x reference)
//
#include <hip/hip_runtime.h>
#include <hip/hip_bf16.h>
#include <math.h>

#define NNODES 20000
#define NEDGES 400000
#define NREL 8

typedef _Float16 h16_t;
typedef _Float16 h16x8 __attribute__((ext_vector_type(8)));
typedef _Float16 h16x4 __attribute__((ext_vector_type(4)));
typedef _Float16 h16x2 __attribute__((ext_vector_type(2)));
typedef float f32x4 __attribute__((ext_vector_type(4)));

struct W3 {
    const float* Wrel[3];
    const float* Wroot[3];
    const float* asrc[3];
    const float* adst[3];
    h16_t* B2a[3];   // agg weights: [dout][2048]  (k = r*256 + kk)
    h16_t* B2r[3];   // root weights: [dout][256]
};

// ---------------------------------------------------------------------------
// Edge preprocessing: per-(dst,rel) counts.
// ---------------------------------------------------------------------------
__global__ void count_edges(const int* __restrict__ ei, const int* __restrict__ et,
                            int* __restrict__ rel_cnt, int E) {
    int e = blockIdx.x * blockDim.x + threadIdx.x;
    if (e >= E) return;
    int d = ei[E + e];
    atomicAdd(&rel_cnt[d * NREL + et[e]], 1);
}

// ---------------------------------------------------------------------------
// Multi-block exclusive scan over the FLAT relcnt array (N*8 entries) so the
// edge sort is grouped by (dst, rel) — required for static per-rel register
// accumulators in attn_pre.
// ---------------------------------------------------------------------------
__global__ __launch_bounds__(1024) void scan_blocks(
    const int* __restrict__ cnts, int* __restrict__ loc,
    int* __restrict__ partials, int n) {
    __shared__ int wsum[16];
    const int i = blockIdx.x * 1024 + threadIdx.x;
    const int lane = threadIdx.x & 63, wid = threadIdx.x >> 6;
    int d = (i < n) ? cnts[i] : 0;
    int s = d;
#pragma unroll
    for (int o = 1; o < 64; o <<= 1) {
        int t = __shfl_up(s, o);
        if (lane >= o) s += t;
    }
    if (lane == 63) wsum[wid] = s;
    __syncthreads();
    if (wid == 0 && lane < 16) {
        int ws = wsum[lane];
#pragma unroll
        for (int o = 1; o < 16; o <<= 1) {
            int t = __shfl_up(ws, o);
            if (lane >= o) ws += t;
        }
        wsum[lane] = ws;
    }
    __syncthreads();
    int excl = ((wid == 0) ? 0 : wsum[wid - 1]) + s - d;
    if (i < n) loc[i] = excl;
    if (threadIdx.x == 1023) partials[blockIdx.x] = wsum[15];
}

// Phase 2: single-wave chunked scan of per-block totals (nb up to 256).
__global__ void scan_partials_k(int* __restrict__ partials, int* __restrict__ off2,
                                int nb, int n2) {
    const int lane = threadIdx.x;
    int carry = 0;
    for (int c0 = 0; c0 < nb; c0 += 64) {
        int idx = c0 + lane;
        int v = (idx < nb) ? partials[idx] : 0;
        int s = v;
#pragma unroll
        for (int o = 1; o < 64; o <<= 1) {
            int t = __shfl_up(s, o);
            if (lane >= o) s += t;
        }
        if (idx < nb) partials[idx] = carry + s - v;
        carry += __shfl(s, 63);
    }
    if (lane == 0) off2[n2] = carry;
}

// Phase 3: add block bases, emit off2 + cursor2.
__global__ __launch_bounds__(1024) void add_offsets(
    const int* __restrict__ loc, const int* __restrict__ partials,
    int* __restrict__ off2, int* __restrict__ cursor2, int n) {
    const int i = blockIdx.x * 1024 + threadIdx.x;
    if (i >= n) return;
    int v = loc[i] + partials[blockIdx.x];
    off2[i] = v;
    cursor2[i] = v;
}

__global__ void scatter_edges(const int* __restrict__ ei, const int* __restrict__ et,
                              int* __restrict__ cursor2, int* __restrict__ sorted, int E) {
    int e = blockIdx.x * blockDim.x + threadIdx.x;
    if (e >= E) return;
    int d = ei[E + e];
    int pos = atomicAdd(&cursor2[d * NREL + et[e]], 1);
    sorted[pos] = ei[e];   // src only; rel implied by segment
}

// ---------------------------------------------------------------------------
// Merged setup: blocks [0,8) rel_proj; [8,1736) watt; [1736,2376) pack
// B2a (agg, [dout][2048]) + B2r (root, [dout][256]) fp16 per layer.
// ---------------------------------------------------------------------------
__global__ __launch_bounds__(256) void setup_k(
    W3 w, const float* __restrict__ rel_emb, const float* __restrict__ rpw,
    const float* __restrict__ rpb, float* __restrict__ rel_proj,
    float* __restrict__ watt) {
    const int b = blockIdx.x;
    if (b < 8) {
        int r = b, j = threadIdx.x;
        float acc = rpb[j];
        for (int i = 0; i < 256; ++i) acc += rel_emb[r * 256 + i] * rpw[i * 256 + j];
        rel_proj[r * 256 + j] = acc;
    } else if (b < 8 + 1728) {
        const int wg = (b - 8) * 4 + (threadIdx.x >> 6);
        const int lane = threadIdx.x & 63;
        const int layer = wg / (9 * 256);
        const int rem = wg % (9 * 256);
        const int idx = rem >> 8, k = rem & 255;
        const int dout = (layer == 2) ? 128 : 256;
        float a = 0.f;
        if (idx < NREL) {
            const float* wrow = w.Wrel[layer] + ((size_t)idx * 256 + k) * dout;
            const float* att = w.asrc[layer];
            for (int j = lane; j < dout; j += 64) a += wrow[j] * att[j];
        } else {
            const float* wrow = w.Wroot[layer] + (size_t)k * dout;
            const float* att = w.adst[layer];
            for (int j = lane; j < dout; j += 64) a += wrow[j] * att[j];
        }
        for (int o = 32; o > 0; o >>= 1) a += __shfl_xor(a, o);
        if (lane == 0) watt[(layer * 9 + idx) * 256 + k] = a;
    } else {
        int bp = b - 1736;
        int layer, n;
        if (bp < 256)      { layer = 0; n = bp; }
        else if (bp < 512) { layer = 1; n = bp - 256; }
        else               { layer = 2; n = bp - 512; }
        const int dout = (layer == 2) ? 128 : 256;
        const int tid = threadIdx.x;
        const float* Wr = w.Wrel[layer];
        h16_t* Ba = w.B2a[layer];
#pragma unroll
        for (int c = 0; c < 8; ++c)   // k = c*256 + tid  ->  r = c, kk = tid
            Ba[(size_t)n * 2048 + c * 256 + tid] =
                (h16_t)Wr[((size_t)c * 256 + tid) * dout + n];
        w.B2r[layer][(size_t)n * 256 + tid] =
            (h16_t)w.Wroot[layer][(size_t)tid * dout + n];
    }
}

// ---------------------------------------------------------------------------
// Layer-0: cast x -> A2 (fp16 [N,256]) + 9 attention dots.
// ---------------------------------------------------------------------------
__global__ __launch_bounds__(256) void cast_score(
    const float* __restrict__ h, const float* __restrict__ watt,
    h16_t* __restrict__ A2, float* __restrict__ s_src, float* __restrict__ s_dst, int n) {
    const int node = (blockIdx.x * blockDim.x + threadIdx.x) >> 6;
    const int lane = threadIdx.x & 63;
    if (node >= n) return;
    float4 v = *(const float4*)(h + (size_t)node * 256 + lane * 4);
    h16x4 hi = {(h16_t)v.x, (h16_t)v.y, (h16_t)v.z, (h16_t)v.w};
    *(h16x4*)(A2 + (size_t)node * 256 + lane * 4) = hi;
#pragma unroll
    for (int idx = 0; idx < 9; ++idx) {
        const float* wv = watt + idx * 256 + lane * 4;
        float a = v.x * wv[0] + v.y * wv[1] + v.z * wv[2] + v.w * wv[3];
        for (int o = 32; o > 0; o >>= 1) a += __shfl_xor(a, o);
        if (lane == 0) {
            if (idx < NREL) s_src[node * NREL + idx] = a;
            else            s_dst[node] = a;
        }
    }
}

// ---------------------------------------------------------------------------
// attn_pre: softmax + per-(node,rel) alpha-weighted pre-aggregation of RAW
// features (A2, 10 MB, L2/L3-resident) -> wagg [N][8*256] fp16.
// The relation transform is applied afterwards by the K=2048 GEMM.
// ---------------------------------------------------------------------------
__global__ __launch_bounds__(256) void attn_pre(
    const int* __restrict__ off2, const int* __restrict__ sorted,
    const float* __restrict__ s_src, const float* __restrict__ s_dst,
    const int* __restrict__ relcnt, const h16_t* __restrict__ A2g,
    h16_t* __restrict__ wagg, int n) {
    __shared__ uint2 pe[4][64];
    const int node = (blockIdx.x * blockDim.x + threadIdx.x) >> 6;
    const int lane = threadIdx.x & 63;
    const int wid  = threadIdx.x >> 6;
    if (node >= n) return;
    const int b8 = node * NREL;
    int4 ca = *(const int4*)(relcnt + b8);
    int4 cb = *(const int4*)(relcnt + b8 + 4);
    int rc[8] = {ca.x, ca.y, ca.z, ca.w, cb.x, cb.y, cb.z, cb.w};
    int cum[8];
    cum[0] = rc[0];
#pragma unroll
    for (int r = 1; r < 8; ++r) cum[r] = cum[r - 1] + rc[r];
    const int deg = cum[7];
    h16_t* wrow = wagg + (size_t)node * 2048 + lane * 4;
    if (deg == 0) {
        h16x4 z = {};
#pragma unroll
        for (int r = 0; r < 8; ++r) *(h16x4*)(wrow + r * 256) = z;
        return;
    }
    const int beg = off2[b8];
    const float sdn = s_dst[node];

    auto run_accum = [&](int j0, int cnt, float* acc) {
        int u = 0;
        for (; u + 4 <= cnt; u += 4) {
            uint2 q0 = pe[wid][j0 + u],     q1 = pe[wid][j0 + u + 1];
            uint2 q2 = pe[wid][j0 + u + 2], q3 = pe[wid][j0 + u + 3];
            h16x4 v0 = *(const h16x4*)(A2g + q0.x + lane * 4);
            h16x4 v1 = *(const h16x4*)(A2g + q1.x + lane * 4);
            h16x4 v2 = *(const h16x4*)(A2g + q2.x + lane * 4);
            h16x4 v3 = *(const h16x4*)(A2g + q3.x + lane * 4);
            float e0 = __uint_as_float(q0.y), e1 = __uint_as_float(q1.y);
            float e2 = __uint_as_float(q2.y), e3 = __uint_as_float(q3.y);
#pragma unroll
            for (int t = 0; t < 4; ++t) {
                acc[t] += e0 * (float)v0[t];
                acc[t] += e1 * (float)v1[t];
                acc[t] += e2 * (float)v2[t];
                acc[t] += e3 * (float)v3[t];
            }
        }
        for (; u < cnt; ++u) {
            uint2 q = pe[wid][j0 + u];
            h16x4 v = *(const h16x4*)(A2g + q.x + lane * 4);
            float e = __uint_as_float(q.y);
#pragma unroll
            for (int t = 0; t < 4; ++t) acc[t] += e * (float)v[t];
        }
    };

    if (deg <= 64) {
        int src = 0, rel = 0; float sc = -1e30f;
        if (lane < deg) {
            src = sorted[beg + lane];
#pragma unroll
            for (int r = 0; r < 7; ++r) rel += (lane >= cum[r]);
            sc = s_src[src * NREL + rel] + sdn;
            sc = sc > 0.f ? sc : 0.2f * sc;
        }
        float m = sc;
        for (int o = 32; o > 0; o >>= 1) m = fmaxf(m, __shfl_xor(m, o));
        float ex = (lane < deg) ? __expf(sc - m) : 0.f;
        float ds = ex;
        for (int o = 32; o > 0; o >>= 1) ds += __shfl_xor(ds, o);
        float inv = 1.f / ds;
        pe[wid][lane] = uint2{(uint32_t)(src * 256), __float_as_uint(ex * inv)};
        __builtin_amdgcn_wave_barrier();
        int j = 0;
        for (int r = 0; r < 8; ++r) {
            float acc[4] = {0.f, 0.f, 0.f, 0.f};
            run_accum(j, rc[r], acc);
            j += rc[r];
            h16x4 o_ = {(h16_t)acc[0], (h16_t)acc[1], (h16_t)acc[2], (h16_t)acc[3]};
            *(h16x4*)(wrow + r * 256) = o_;
        }
    } else {
        // rare heavy nodes: dedicated max + dsum passes, then per-rel chunks
        float m = -1e30f;
        for (int e = lane; e < deg; e += 64) {
            int src = sorted[beg + e];
            int rel = 0;
#pragma unroll
            for (int r = 0; r < 7; ++r) rel += (e >= cum[r]);
            float sc = s_src[src * NREL + rel] + sdn;
            sc = sc > 0.f ? sc : 0.2f * sc;
            m = fmaxf(m, sc);
        }
        for (int o = 32; o > 0; o >>= 1) m = fmaxf(m, __shfl_xor(m, o));
        float ds = 0.f;
        for (int e = lane; e < deg; e += 64) {
            int src = sorted[beg + e];
            int rel = 0;
#pragma unroll
            for (int r = 0; r < 7; ++r) rel += (e >= cum[r]);
            float sc = s_src[src * NREL + rel] + sdn;
            sc = sc > 0.f ? sc : 0.2f * sc;
            ds += __expf(sc - m);
        }
        for (int o = 32; o > 0; o >>= 1) ds += __shfl_xor(ds, o);
        float inv = 1.f / ds;
        int bstart = 0;
        for (int r = 0; r < 8; ++r) {
            float acc[4] = {0.f, 0.f, 0.f, 0.f};
            const int cnt = rc[r];
            for (int c0 = 0; c0 < cnt; c0 += 64) {
                int k = cnt - c0; if (k > 64) k = 64;
                if (lane < k) {
                    int src = sorted[beg + bstart + c0 + lane];
                    float sc = s_src[src * NREL + r] + sdn;
                    sc = sc > 0.f ? sc : 0.2f * sc;
                    pe[wid][lane] = uint2{(uint32_t)(src * 256),
                                          __float_as_uint(__expf(sc - m) * inv)};
                }
                __builtin_amdgcn_wave_barrier();
                run_accum(0, k, acc);
                __builtin_amdgcn_wave_barrier();
            }
            bstart += cnt;
            h16x4 o_ = {(h16_t)acc[0], (h16_t)acc[1], (h16_t)acc[2], (h16_t)acc[3]};
            *(h16x4*)(wrow + r * 256) = o_;
        }
    }
}

// ---------------------------------------------------------------------------
// GEMM: per column-block either agg (A=wagg, K=2048, B=B2a) or root
// (A=A2, K=256, B=B2r). Same MFMA tile count as the old hr-GEMM.
// ---------------------------------------------------------------------------
#define GBM 128
#define GBN 128
#define GBK 64

__global__ __launch_bounds__(256) void gemm2(
    const h16_t* __restrict__ wagg, const h16_t* __restrict__ A2,
    const h16_t* __restrict__ Ba, const h16_t* __restrict__ Br,
    h16_t* __restrict__ aggf, h16_t* __restrict__ rootf, int M, int dout) {
    __shared__ __align__(16) h16_t As[GBM * GBK];
    __shared__ __align__(16) h16_t Bs[GBN * GBK];
    const int nAgg = dout >> 7;
    const int bx = blockIdx.x;
    const bool isAgg = bx < nAgg;
    const int K = isAgg ? 2048 : 256;
    const h16_t* A = isAgg ? wagg : A2;
    const int col0 = (isAgg ? bx : bx - nAgg) << 7;
    const h16_t* B = (isAgg ? Ba : Br) + (size_t)col0 * K;
    const int tid  = threadIdx.x;
    const int lane = tid & 63;
    const int w    = tid >> 6;
    const int row0 = blockIdx.y * GBM;
    const int wm   = (w >> 1) * 64;
    const int wn   = (w & 1) * 64;

    f32x4 acc[4][4] = {};

    for (int kb = 0; kb < K; kb += GBK) {
#pragma unroll
        for (int i = 0; i < 4; ++i) {
            int c  = i * 256 + tid;
            int r  = c >> 3;
            int cl = (c & 7) ^ (r & 7);
            int ra = row0 + r; if (ra >= M) ra = M - 1;
            const h16_t* ga = A + (size_t)ra * K + kb + cl * 8;
            __builtin_amdgcn_global_load_lds(
                (const __attribute__((address_space(1))) void*)ga,
                (__attribute__((address_space(3))) void*)(As + (size_t)c * 8), 16, 0, 0);
            const h16_t* gb = B + (size_t)r * K + kb + cl * 8;
            __builtin_amdgcn_global_load_lds(
                (const __attribute__((address_space(1))) void*)gb,
                (__attribute__((address_space(3))) void*)(Bs + (size_t)c * 8), 16, 0, 0);
        }
        __syncthreads();

        const int q = lane >> 4;
#pragma unroll
        for (int kk = 0; kk < 2; ++kk) {
            const int cf = kk * 4 + q;
            h16x8 af[4], bfr[4];
#pragma unroll
            for (int t = 0; t < 4; ++t) {
                int rr = wm + t * 16 + (lane & 15);
                af[t] = *(const h16x8*)(As + rr * GBK + (cf ^ (rr & 7)) * 8);
                int rcb = wn + t * 16 + (lane & 15);
                bfr[t] = *(const h16x8*)(Bs + rcb * GBK + (cf ^ (rcb & 7)) * 8);
            }
#pragma unroll
            for (int mt = 0; mt < 4; ++mt)
#pragma unroll
                for (int nt = 0; nt < 4; ++nt)
                    acc[mt][nt] = __builtin_amdgcn_mfma_f32_16x16x32_f16(
                        af[mt], bfr[nt], acc[mt][nt], 0, 0, 0);
        }
        __syncthreads();
    }

    h16_t* dst = isAgg ? aggf : rootf;
#pragma unroll
    for (int mt = 0; mt < 4; ++mt) {
#pragma unroll
        for (int reg = 0; reg < 4; ++reg) {
            int row = row0 + wm + mt * 16 + (lane >> 4) * 4 + reg;
            if (row >= M) continue;
#pragma unroll
            for (int nt = 0; nt < 4; ++nt) {
                int col = col0 + wn + nt * 16 + (lane & 15);
                dst[(size_t)row * dout + col] = (h16_t)acc[mt][nt][reg];
            }
        }
    }
}

// ---------------------------------------------------------------------------
// Per-node epilogue. MODE 0: t = A2_old + relu(root + agg + rsum); writes
// A2 (next-layer input) + next-layer attention scores. MODE 1: out=root+agg.
// ---------------------------------------------------------------------------
template <int DO, int MODE>
__global__ __launch_bounds__(256) void node_epi(
    const h16_t* __restrict__ rootf, const h16_t* __restrict__ aggf,
    const int* __restrict__ relcnt, const float* __restrict__ relproj,
    const float* __restrict__ watt_next, h16_t* __restrict__ A2,
    float* __restrict__ ssrc_out, float* __restrict__ sdst_out,
    float* __restrict__ out, int n) {
    const int node = (blockIdx.x * blockDim.x + threadIdx.x) >> 6;
    const int lane = threadIdx.x & 63;
    if (node >= n) return;
    constexpr int PER = DO / 64;
    const int cbase = lane * PER;
    if constexpr (MODE == 0) {
        float rsum[PER];
#pragma unroll
        for (int j = 0; j < PER; ++j) rsum[j] = 0.f;
#pragma unroll
        for (int r = 0; r < NREL; ++r) {
            float cr = (float)relcnt[node * NREL + r];
            const float* rp = relproj + r * 256 + cbase;
#pragma unroll
            for (int j = 0; j < PER; ++j) rsum[j] += cr * rp[j];
        }
        h16x4 hp = *(const h16x4*)(A2 + (size_t)node * 256 + cbase);
        h16x4 rt = *(const h16x4*)(rootf + (size_t)node * DO + cbase);
        h16x4 ag = *(const h16x4*)(aggf + (size_t)node * DO + cbase);
        float t[PER];
#pragma unroll
        for (int j = 0; j < PER; ++j) {
            float u = (float)rt[j] + (float)ag[j] + rsum[j];
            u = u > 0.f ? u : 0.f;
            t[j] = (float)hp[j] + u;
        }
        h16x4 hi;
#pragma unroll
        for (int j = 0; j < PER; ++j) hi[j] = (h16_t)t[j];
        *(h16x4*)(A2 + (size_t)node * 256 + cbase) = hi;
#pragma unroll
        for (int idx = 0; idx < 9; ++idx) {
            const float* wv = watt_next + idx * 256 + cbase;
            float a = 0.f;
#pragma unroll
            for (int j = 0; j < PER; ++j) a += t[j] * wv[j];
            for (int o = 32; o > 0; o >>= 1) a += __shfl_xor(a, o);
            if (lane == 0) {
                if (idx < NREL) ssrc_out[node * NREL + idx] = a;
                else            sdst_out[node] = a;
            }
        }
    } else {
        h16x2 rt = *(const h16x2*)(rootf + (size_t)node * DO + cbase);
        h16x2 ag = *(const h16x2*)(aggf + (size_t)node * DO + cbase);
#pragma unroll
        for (int j = 0; j < PER; ++j)
            out[(size_t)node * DO + cbase + j] = (float)rt[j] + (float)ag[j];
    }
}

// ---------------------------------------------------------------------------
extern "C" void kernel_launch(void* const* d_in, const int* in_sizes, int n_in,
                              void* d_out, int out_size, void* d_ws, size_t ws_size,
                              hipStream_t stream) {
    const int N = NNODES, E = NEDGES;
    const float* x        = (const float*)d_in[0];
    const int*   ei       = (const int*)d_in[1];
    const int*   et       = (const int*)d_in[2];
    const float* rel_emb  = (const float*)d_in[3];
    const float* rpw      = (const float*)d_in[4];
    const float* rpb      = (const float*)d_in[5];
    float* outp = (float*)d_out;

    W3 w3;
    for (int l = 0; l < 3; ++l) {
        w3.Wrel[l]  = (const float*)d_in[6 + 4 * l];
        w3.Wroot[l] = (const float*)d_in[7 + 4 * l];
        w3.asrc[l]  = (const float*)d_in[8 + 4 * l];
        w3.adst[l]  = (const float*)d_in[9 + 4 * l];
    }

    // Workspace (~120 MB of 256 MiB budget).
    char* w = (char*)d_ws;
    auto alloc = [&](size_t bytes) { char* p = w; w += (bytes + 255) & ~(size_t)255; return p; };
    h16_t* wagg    = (h16_t*)alloc((size_t)N * 2048 * 2);   // 81.9 MB (L3-resident)
    h16_t* aggf    = (h16_t*)alloc((size_t)N * 256 * 2);    // 10.2 MB
    h16_t* rootf   = (h16_t*)alloc((size_t)N * 256 * 2);    // 10.2 MB
    float* relproj = (float*)alloc(NREL * 256 * 4);
    float* watt    = (float*)alloc(3 * 9 * 256 * 4);
    float* ssrcA   = (float*)alloc((size_t)N * NREL * 4);
    float* sdstA   = (float*)alloc((size_t)N * 4);
    float* ssrcB   = (float*)alloc((size_t)N * NREL * 4);
    float* sdstB   = (float*)alloc((size_t)N * 4);
    h16_t* A2      = (h16_t*)alloc((size_t)N * 256 * 2);    // 10.2 MB (gather target)
    w3.B2a[0]      = (h16_t*)alloc((size_t)256 * 2048 * 2); // 1 MB
    w3.B2a[1]      = (h16_t*)alloc((size_t)256 * 2048 * 2);
    w3.B2a[2]      = (h16_t*)alloc((size_t)128 * 2048 * 2);
    w3.B2r[0]      = (h16_t*)alloc((size_t)256 * 256 * 2);
    w3.B2r[1]      = (h16_t*)alloc((size_t)256 * 256 * 2);
    w3.B2r[2]      = (h16_t*)alloc((size_t)128 * 256 * 2);
    int* off2      = (int*)alloc(((size_t)N * NREL + 1) * 4);
    int* cursor2   = (int*)alloc((size_t)N * NREL * 4);
    int* relcnt    = (int*)alloc((size_t)N * NREL * 4);
    int* sorted    = (int*)alloc((size_t)E * 4);
    int* loc       = (int*)alloc((size_t)N * NREL * 4);
    int* partials  = (int*)alloc(256 * 4);
    (void)ws_size; (void)in_sizes; (void)n_in; (void)out_size;

    hipMemsetAsync(relcnt, 0, (size_t)N * NREL * 4, stream);

    const int EB  = (E + 255) / 256;
    const int n2  = N * NREL;                 // 160000
    const int NB2 = (n2 + 1023) / 1024;       // 157 blocks
    count_edges<<<EB, 256, 0, stream>>>(ei, et, relcnt, E);
    scan_blocks<<<NB2, 1024, 0, stream>>>(relcnt, loc, partials, n2);
    scan_partials_k<<<1, 64, 0, stream>>>(partials, off2, NB2, n2);
    add_offsets<<<NB2, 1024, 0, stream>>>(loc, partials, off2, cursor2, n2);
    scatter_edges<<<EB, 256, 0, stream>>>(ei, et, cursor2, sorted, E);
    setup_k<<<2376, 256, 0, stream>>>(w3, rel_emb, rpw, rpb, relproj, watt);

    const int ATB  = (N + 3) / 4;
    const int MBLK = (N + GBM - 1) / GBM;   // 157

    // layer 0
    cast_score<<<ATB, 256, 0, stream>>>(x, watt, A2, ssrcA, sdstA, N);
    attn_pre<<<ATB, 256, 0, stream>>>(off2, sorted, ssrcA, sdstA, relcnt, A2, wagg, N);
    gemm2<<<dim3(4, MBLK), 256, 0, stream>>>(wagg, A2, w3.B2a[0], w3.B2r[0],
                                             aggf, rootf, N, 256);
    node_epi<256, 0><<<ATB, 256, 0, stream>>>(rootf, aggf, relcnt, relproj,
                                              watt + 9 * 256, A2, ssrcB, sdstB,
                                              nullptr, N);
    // layer 1
    attn_pre<<<ATB, 256, 0, stream>>>(off2, sorted, ssrcB, sdstB, relcnt, A2, wagg, N);
    gemm2<<<dim3(4, MBLK), 256, 0, stream>>>(wagg, A2, w3.B2a[1], w3.B2r[1],
                                             aggf, rootf, N, 256);
    node_epi<256, 0><<<ATB, 256, 0, stream>>>(rootf, aggf, relcnt, relproj,
                                              watt + 2 * 9 * 256, A2, ssrcA, sdstA,
                                              nullptr, N);
    // layer 2
    attn_pre<<<ATB, 256, 0, stream>>>(off2, sorted, ssrcA, sdstA, relcnt, A2, wagg, N);
    gemm2<<<dim3(2, MBLK), 256, 0, stream>>>(wagg, A2, w3.B2a[2], w3.B2r[2],
                                             aggf, rootf, N, 128);
    node_epi<128, 1><<<ATB, 256, 0, stream>>>(rootf, aggf, nullptr, nullptr,
                                              nullptr, nullptr, nullptr, nullptr,
                                              outp, N);
}